// Round 10
// baseline (37.313 us; speedup 1.0000x reference)
//
#include <hip/hip_runtime.h>

// MPS batched contraction via SITE PAIRING (R9-verified):
// G_P[l][pq][d] = Σ_m A_{2P}[l,p,m] A_{2P+1}[m,q,d],  xx[pq] = x_p * y_q,
// left'' = G_P(xx) left.  32 pairs, 16x16x32 f16 MFMA, K=128 per pair
// (4 khalf frags x 2 d-halves).  k = 32*kh + 8*g + (l&3) + 4*(l>>4) makes
// U same-lane: U_kh[e] = f16(acc_{e>>2}[e&3]) * xx[kh].
//
// R10: FOUR 16-row tiles per wave share the G-frag registers. 1024 waves
// (4/CU, 1/SIMD) -> per-CU LDS G-read traffic halves vs R9 (1024 b128/CU
// ~ 5.1us wall); latency hiding now via ILP (4 independent acc chains/wave)
// instead of TLP. 512 blocks x 128 thr = 2 blocks/CU (independent barrier
// groups overlap each other's stalls). launch_bounds(128,1) -> VGPR cap 512
// so the ~300-reg pipeline (acc 64 + G 64 + x 128) actually materializes.

typedef _Float16 h2 __attribute__((ext_vector_type(2)));
typedef _Float16 half8 __attribute__((ext_vector_type(8)));
typedef float floatx4 __attribute__((ext_vector_type(4)));
typedef float f32x4 __attribute__((ext_vector_type(4)));

#define NPAIRS 32
#define CHUNK_ELEMS 16384   // 4 pairs * 8 frags * 64 lanes * 8 halfs = 32KB

// ---------------- prep: pair products + fragment packing (same as R9) -----
__global__ void mps_prep_pair(const float* __restrict__ A, _Float16* __restrict__ Gf) {
    __shared__ float sA0[2048], sA1[2048], sG[4096];
    const int P = blockIdx.x, tid = threadIdx.x;
    const float* a0p = A + (size_t)(2 * P) * 2048;
    const float* a1p = A + (size_t)(2 * P + 1) * 2048;
#pragma unroll
    for (int i = 0; i < 8; ++i) {
        sA0[tid + 256 * i] = a0p[tid + 256 * i];
        sA1[tid + 256 * i] = a1p[tid + 256 * i];
    }
    __syncthreads();
    {   // thread -> (l, pq, d-half): 16 outputs, dot over m=32 in f32
        const int l = tid >> 3, pq = (tid >> 1) & 3, dh16 = (tid & 1) * 16;
        const int p = pq >> 1, q = pq & 1;
        float accv[16];
#pragma unroll
        for (int dd = 0; dd < 16; ++dd) accv[dd] = 0.f;
        for (int m = 0; m < 32; ++m) {
            const float av = sA0[l * 64 + p * 32 + m];
            const float* bp = &sA1[m * 64 + q * 32 + dh16];
#pragma unroll
            for (int dd = 0; dd < 16; ++dd) accv[dd] += av * bp[dd];
        }
#pragma unroll
        for (int dd = 0; dd < 16; ++dd) sG[l * 128 + pq * 32 + dh16 + dd] = accv[dd];
    }
    __syncthreads();
    const int lane = tid & 63, g = lane >> 4;
#pragma unroll
    for (int pass = 0; pass < 2; ++pass) {
        const int fr = (tid >> 6) + pass * 2;      // 2 waves -> frs 0..3 need 4 passes
        // NOTE: 128-thread grid would need 4 passes; prep uses 256 threads (below)
        (void)fr;
    }
    // packing with 256 threads: fr = tid>>6 (0..3) then +4
    {
        const int lane2 = tid & 63, g2 = lane2 >> 4;
#pragma unroll
        for (int pass = 0; pass < 2; ++pass) {
            const int fr = (tid >> 6) + pass * 4;  // 0..7
            const int dh = fr >> 2, kh = fr & 3;
            const int d  = 16 * dh + (lane2 & 15);
            half8 v;
#pragma unroll
            for (int e = 0; e < 8; ++e) {
                const int l = 4 * g2 + (e & 3) + 16 * (e >> 2);
                v[e] = (_Float16)sG[l * 128 + kh * 32 + d];
            }
            reinterpret_cast<half8*>(Gf)[((size_t)P * 8 + fr) * 64 + lane2] = v;
        }
    }
}

// ---------------- main kernel ----------------
static __device__ __forceinline__ half8 H8(h2 a, h2 b, h2 c, h2 d) {
    half8 r;
    r[0] = a[0]; r[1] = a[1]; r[2] = b[0]; r[3] = b[1];
    r[4] = c[0]; r[5] = c[1]; r[6] = d[0]; r[7] = d[1];
    return r;
}

#define MF(A_, B_, C_) __builtin_amdgcn_mfma_f32_16x16x32_f16(A_, B_, C_, 0, 0, 0)

// U-frags for one tile from acc halves + x quad XV=(x0,x1,y0,y1).
#define UB(U0, U1, U2, U3, AH0, AH1, XV)                                      \
    {                                                                         \
        h2 b0, b1, b2, b3, w0, w1, w2, w3;                                    \
        b0[0] = (_Float16)AH0[0]; b0[1] = (_Float16)AH0[1];                   \
        b1[0] = (_Float16)AH0[2]; b1[1] = (_Float16)AH0[3];                   \
        b2[0] = (_Float16)AH1[0]; b2[1] = (_Float16)AH1[1];                   \
        b3[0] = (_Float16)AH1[2]; b3[1] = (_Float16)AH1[3];                   \
        _Float16 t_;                                                          \
        t_ = (_Float16)(XV[0] * XV[2]); w0[0] = t_; w0[1] = t_;               \
        t_ = (_Float16)(XV[0] * XV[3]); w1[0] = t_; w1[1] = t_;               \
        t_ = (_Float16)(XV[1] * XV[2]); w2[0] = t_; w2[1] = t_;               \
        t_ = (_Float16)(XV[1] * XV[3]); w3[0] = t_; w3[1] = t_;               \
        U0 = H8(b0 * w0, b1 * w0, b2 * w0, b3 * w0);                          \
        U1 = H8(b0 * w1, b1 * w1, b2 * w1, b3 * w1);                          \
        U2 = H8(b0 * w2, b1 * w2, b2 * w2, b3 * w2);                          \
        U3 = H8(b0 * w3, b1 * w3, b2 * w3, b3 * w3);                          \
    }

// One pair, ONE tile. G[fr]: fr = dh*4+kh. 8 MFMAs, two 4-deep chains.
#define PAIR1(G, I0, I1, O0, O1, XV)                                          \
    {                                                                         \
        half8 u0_, u1_, u2_, u3_;                                             \
        UB(u0_, u1_, u2_, u3_, I0, I1, XV)                                    \
        O0 = MF(G[0], u0_, zv);  O1 = MF(G[4], u0_, zv);                      \
        O0 = MF(G[1], u1_, O0);  O1 = MF(G[5], u1_, O1);                      \
        O0 = MF(G[2], u2_, O0);  O1 = MF(G[6], u2_, O1);                      \
        O0 = MF(G[3], u3_, O0);  O1 = MF(G[7], u3_, O1);                      \
    }

// One pair for all 4 tiles; even pairs a->n, odd pairs n->a.
#define PAIR4_E(G, XC, PP)                                                    \
    PAIR1(G, a0h0, a0h1, n0h0, n0h1, XC[0][PP])                               \
    PAIR1(G, a1h0, a1h1, n1h0, n1h1, XC[1][PP])                               \
    PAIR1(G, a2h0, a2h1, n2h0, n2h1, XC[2][PP])                               \
    PAIR1(G, a3h0, a3h1, n3h0, n3h1, XC[3][PP])
#define PAIR4_O(G, XC, PP)                                                    \
    PAIR1(G, n0h0, n0h1, a0h0, a0h1, XC[0][PP])                               \
    PAIR1(G, n1h0, n1h1, a1h0, a1h1, XC[1][PP])                               \
    PAIR1(G, n2h0, n2h1, a2h0, a2h1, XC[2][PP])                               \
    PAIR1(G, n3h0, n3h1, a3h0, a3h1, XC[3][PP])

// Read pair PL (local to chunk buffer BUF) 8 frags into register slot DST.
#define RD(DST, BUF, PL)                                                      \
    {                                                                         \
        _Pragma("unroll")                                                     \
        for (int f_ = 0; f_ < 8; ++f_)                                        \
            DST[f_] = *(const half8*)&smA[(BUF) * CHUNK_ELEMS                 \
                                          + (((PL) * 8 + f_) * 64 + lane) * 8]; \
    }

// Stage chunk C (4 pairs, 32 recs of 1KB) into buffer BUF. 2 waves x 16 recs.
#define STAGE(C, BUF)                                                         \
    {                                                                         \
        _Pragma("unroll")                                                     \
        for (int r_ = 0; r_ < 16; ++r_) {                                     \
            const int rec_ = r_ * 2 + wid;                                    \
            const _Float16* g_ = Gf + (size_t)(C) * CHUNK_ELEMS               \
                                 + rec_ * 512 + lane * 8;                     \
            __builtin_amdgcn_global_load_lds(                                 \
                (const __attribute__((address_space(1))) void*)g_,            \
                (__attribute__((address_space(3))) void*)&smA[(BUF) * CHUNK_ELEMS + rec_ * 512], \
                16, 0, 0);                                                    \
        }                                                                     \
    }

// One 4-pair chunk: stage next chunk + prefetch next x (4 tiles) up front,
// 2-slot register G pipeline, barrier, pre-read next chunk's pair 0.
#define CHUNKB(C, BUF, XC, XN)                                                \
    {                                                                         \
        if ((C) < 7) {                                                        \
            STAGE((C) + 1, 1 - (BUF));                                        \
            _Pragma("unroll")                                                 \
            for (int tt_ = 0; tt_ < 4; ++tt_)                                 \
                _Pragma("unroll")                                             \
                for (int pp_ = 0; pp_ < 4; ++pp_)                             \
                    XN[tt_][pp_] = xp[tt_][4 * ((C) + 1) + pp_];              \
        }                                                                     \
        RD(GB, BUF, 1)                                                        \
        PAIR4_E(GA, XC, 0)                                                    \
        RD(GA, BUF, 2)                                                        \
        PAIR4_O(GB, XC, 1)                                                    \
        RD(GB, BUF, 3)                                                        \
        PAIR4_E(GA, XC, 2)                                                    \
        PAIR4_O(GB, XC, 3)                                                    \
        __syncthreads();                                                      \
        if ((C) < 7) RD(GA, 1 - (BUF), 0)                                     \
    }

__global__ __launch_bounds__(128, 1) void mps_main(const float* __restrict__ x,
                                                   const _Float16* __restrict__ Gf,
                                                   float* __restrict__ out) {
    __shared__ __align__(16) _Float16 smA[2 * CHUNK_ELEMS];   // 64KB

    const int lane  = threadIdx.x & 63;
    const int wid   = threadIdx.x >> 6;               // 0..1
    const int wbase = (blockIdx.x * 2 + wid) * 64;    // 64 rows per wave (4 tiles)
    const int r     = lane & 15;

    const f32x4* xp[4];
#pragma unroll
    for (int tt = 0; tt < 4; ++tt)
        xp[tt] = reinterpret_cast<const f32x4*>(x + (size_t)(wbase + 16 * tt + r) * 128);

    floatx4 zv;
#pragma unroll
    for (int i = 0; i < 4; ++i) zv[i] = 0.f;

    // acc: tile t halves (tNh0 = left[0..15], tNh1 = left[16..31]); n* partners
    floatx4 a0h0, a0h1, a1h0, a1h1, a2h0, a2h1, a3h0, a3h1;
    floatx4 n0h0, n0h1, n1h0, n1h1, n2h0, n2h1, n3h0, n3h1;
#pragma unroll
    for (int i = 0; i < 4; ++i) {
        a0h0[i] = a0h1[i] = a1h0[i] = a1h1[i] = 0.f;
        a2h0[i] = a2h1[i] = a3h0[i] = a3h1[i] = 0.f;
        n0h0[i] = n0h1[i] = n1h0[i] = n1h1[i] = 0.f;
        n2h0[i] = n2h1[i] = n3h0[i] = n3h1[i] = 0.f;
    }
    if (lane < 16) { a0h0[0] = 1.f; a1h0[0] = 1.f; a2h0[0] = 1.f; a3h0[0] = 1.f; }

    f32x4 xa[4][4], xb[4][4];
    half8 GA[8], GB[8];

    STAGE(0, 0);
#pragma unroll
    for (int tt = 0; tt < 4; ++tt)
#pragma unroll
        for (int pp = 0; pp < 4; ++pp) xa[tt][pp] = xp[tt][pp];
    __syncthreads();
    RD(GA, 0, 0)

    CHUNKB(0, 0, xa, xb)
    CHUNKB(1, 1, xb, xa)
    CHUNKB(2, 0, xa, xb)
    CHUNKB(3, 1, xb, xa)
    CHUNKB(4, 0, xa, xb)
    CHUNKB(5, 1, xb, xa)
    CHUNKB(6, 0, xa, xb)
    CHUNKB(7, 1, xb, xa)

    // out[b] = left_final[0]: half0 reg0, lane group 0 (32 pairs even -> a*)
    if (lane < 16) {
        out[wbase + lane]      = a0h0[0];
        out[wbase + 16 + lane] = a1h0[0];
        out[wbase + 32 + lane] = a2h0[0];
        out[wbase + 48 + lane] = a3h0[0];
    }
}

extern "C" void kernel_launch(void* const* d_in, const int* in_sizes, int n_in,
                              void* d_out, int out_size, void* d_ws, size_t ws_size,
                              hipStream_t stream) {
    const float* x = (const float*)d_in[0];   // [65536][64][2] f32
    const float* A = (const float*)d_in[1];   // [64][32][2][32] f32
    float* outp = (float*)d_out;              // [65536] f32
    _Float16* Gf = (_Float16*)d_ws;           // 256 KB pair-fragment fp16

    hipLaunchKernelGGL(mps_prep_pair, dim3(NPAIRS), dim3(256), 0, stream, A, Gf);
    hipLaunchKernelGGL(mps_main, dim3(65536 / 128), dim3(128), 0, stream, x, Gf, outp);
}

// Round 11
// 29.244 us; speedup vs baseline: 1.2759x; 1.2759x over previous
//
#include <hip/hip_runtime.h>

// MPS batched contraction via SITE PAIRING (R9-verified algebra):
// G_P[l][pq][d] = Σ_m A_{2P}[l,p,m] A_{2P+1}[m,q,d],  xx[pq] = x_p * y_q,
// left'' = G_P(xx) left.  32 pairs, K=128 each.
//
// R11: 32x32x16 f16 MFMA (R1-verified A/B operand layout, m74 C/D layout):
//   A-op (G): row d = lane&31, k = 8*(lane>>5) + e   (e = 0..7, half8)
//   B-op (U): col b = lane&31, same k
//   C/D: col = lane&31, row l = (reg&3) + 8*(reg>>2) + 4*(lane>>5)
// G-frag kf = 0..7 per pair encodes k_global = 16*kf + 8*h + e with
//   pq = kf>>1, lh = kf&1, l = 16*lh + (e&3) + 8*(e>>2) + 4*h
// => U_frag(kf) = f16(acc[e + 8*lh]) * xx[pq]  -- SAME LANE, and the f16
// acc (FA0/FA1) is shared across all 8 frags: 16 cvt + 4 mul + 4 cvt +
// 32 pk_mul per pair per 32-row tile.
//
// Why: across R1-R10 the binding wall is LDS G-delivery = 256KB x waves;
// traffic/CU ∝ 1/(rows per wave). 64 rows/wave (2 tiles of 32) halves the
// LDS wall vs R9 (~5us) while the 32x32 shape keeps the register set ~210
// (R10's 4x16-tile variant needed ~300 and the allocator destroyed it at
// 132). 512 blocks x 128 thr = 2 blocks/CU staggered; launch_bounds(128,1).

typedef _Float16 half8 __attribute__((ext_vector_type(8)));
typedef float floatx16 __attribute__((ext_vector_type(16)));
typedef float f32x4 __attribute__((ext_vector_type(4)));

#define NPAIRS 32
#define CHUNK_ELEMS 16384   // 4 pairs * 8 frags * 64 lanes * 8 halfs = 32KB

// ---------------- prep: pair products + fragment packing ----------------
__global__ void mps_prep_pair(const float* __restrict__ A, _Float16* __restrict__ Gf) {
    __shared__ float sA0[2048], sA1[2048], sG[4096];
    const int P = blockIdx.x, tid = threadIdx.x;      // 256 threads
    const float* a0p = A + (size_t)(2 * P) * 2048;
    const float* a1p = A + (size_t)(2 * P + 1) * 2048;
#pragma unroll
    for (int i = 0; i < 8; ++i) {
        sA0[tid + 256 * i] = a0p[tid + 256 * i];
        sA1[tid + 256 * i] = a1p[tid + 256 * i];
    }
    __syncthreads();
    {   // thread -> (l, pq, d-half): 16 outputs, dot over m=32 in f32
        const int l = tid >> 3, pq = (tid >> 1) & 3, dh16 = (tid & 1) * 16;
        const int p = pq >> 1, q = pq & 1;
        float accv[16];
#pragma unroll
        for (int dd = 0; dd < 16; ++dd) accv[dd] = 0.f;
        for (int m = 0; m < 32; ++m) {
            const float av = sA0[l * 64 + p * 32 + m];
            const float* bp = &sA1[m * 64 + q * 32 + dh16];
#pragma unroll
            for (int dd = 0; dd < 16; ++dd) accv[dd] += av * bp[dd];
        }
#pragma unroll
        for (int dd = 0; dd < 16; ++dd) sG[l * 128 + pq * 32 + dh16 + dd] = accv[dd];
    }
    __syncthreads();
    // pack: frag kf of pair P, lane: v[e] = G[l][pq][d], d = lane&31,
    // pq = kf>>1, l = 16*(kf&1) + (e&3) + 8*(e>>2) + 4*(lane>>5)
    const int lane = tid & 63;
    const int h    = lane >> 5;
    const int d    = lane & 31;
#pragma unroll
    for (int pass = 0; pass < 2; ++pass) {
        const int kf = (tid >> 6) + pass * 4;         // 0..7
        const int pq = kf >> 1, lh = kf & 1;
        half8 v;
#pragma unroll
        for (int e = 0; e < 8; ++e) {
            const int l = 16 * lh + (e & 3) + 8 * (e >> 2) + 4 * h;
            v[e] = (_Float16)sG[l * 128 + pq * 32 + d];
        }
        reinterpret_cast<half8*>(Gf)[((size_t)P * 8 + kf) * 64 + lane] = v;
    }
}

// ---------------- main kernel ----------------
#define MF32(A_, B_, C_) __builtin_amdgcn_mfma_f32_32x32x16_f16(A_, B_, C_, 0, 0, 0)

// One pair for one 32-row tile: CIN (floatx16) -> COUT.  8-deep MFMA chain.
#define PAIR1(G, CIN, COUT, XV)                                               \
    {                                                                         \
        half8 FA0_, FA1_;                                                     \
        _Pragma("unroll")                                                     \
        for (int i_ = 0; i_ < 8; ++i_) {                                      \
            FA0_[i_] = (_Float16)CIN[i_];                                     \
            FA1_[i_] = (_Float16)CIN[8 + i_];                                 \
        }                                                                     \
        const _Float16 w0_ = (_Float16)(XV[0] * XV[2]);                       \
        const _Float16 w1_ = (_Float16)(XV[0] * XV[3]);                       \
        const _Float16 w2_ = (_Float16)(XV[1] * XV[2]);                       \
        const _Float16 w3_ = (_Float16)(XV[1] * XV[3]);                       \
        half8 W0_, W1_, W2_, W3_;                                             \
        _Pragma("unroll")                                                     \
        for (int i_ = 0; i_ < 8; ++i_) {                                      \
            W0_[i_] = w0_; W1_[i_] = w1_; W2_[i_] = w2_; W3_[i_] = w3_;       \
        }                                                                     \
        COUT = MF32(G[0], FA0_ * W0_, zv);                                    \
        COUT = MF32(G[1], FA1_ * W0_, COUT);                                  \
        COUT = MF32(G[2], FA0_ * W1_, COUT);                                  \
        COUT = MF32(G[3], FA1_ * W1_, COUT);                                  \
        COUT = MF32(G[4], FA0_ * W2_, COUT);                                  \
        COUT = MF32(G[5], FA1_ * W2_, COUT);                                  \
        COUT = MF32(G[6], FA0_ * W3_, COUT);                                  \
        COUT = MF32(G[7], FA1_ * W3_, COUT);                                  \
    }

// Read pair PL (local to chunk buffer BUF) 8 frags into register slot DST.
#define RD(DST, BUF, PL)                                                      \
    {                                                                         \
        _Pragma("unroll")                                                     \
        for (int f_ = 0; f_ < 8; ++f_)                                        \
            DST[f_] = *(const half8*)&smA[(BUF) * CHUNK_ELEMS                 \
                                          + (((PL) * 8 + f_) * 64 + lane) * 8]; \
    }

// Stage chunk C (4 pairs, 32 recs of 1KB) into buffer BUF. 2 waves x 16 recs.
#define STAGE(C, BUF)                                                         \
    {                                                                         \
        _Pragma("unroll")                                                     \
        for (int r_ = 0; r_ < 16; ++r_) {                                     \
            const int rec_ = r_ * 2 + wid;                                    \
            const _Float16* g_ = Gf + (size_t)(C) * CHUNK_ELEMS               \
                                 + rec_ * 512 + lane * 8;                     \
            __builtin_amdgcn_global_load_lds(                                 \
                (const __attribute__((address_space(1))) void*)g_,            \
                (__attribute__((address_space(3))) void*)&smA[(BUF) * CHUNK_ELEMS + rec_ * 512], \
                16, 0, 0);                                                    \
        }                                                                     \
    }

// One 4-pair chunk: stage next chunk + prefetch next x up front, 2-slot
// register G pipeline (GA/GB), barrier, pre-read next chunk's pair 0.
// Tiles ping-pong c->d (even local pair) / d->c (odd local pair).
#define CHUNKB(C, BUF, XT0, XT1, XN0, XN1)                                    \
    {                                                                         \
        if ((C) < 7) {                                                        \
            STAGE((C) + 1, 1 - (BUF));                                        \
            _Pragma("unroll")                                                 \
            for (int pp_ = 0; pp_ < 4; ++pp_) {                               \
                XN0[pp_] = xp0[4 * ((C) + 1) + pp_];                          \
                XN1[pp_] = xp1[4 * ((C) + 1) + pp_];                          \
            }                                                                 \
        }                                                                     \
        RD(GB, BUF, 1)                                                        \
        PAIR1(GA, c0, d0, XT0[0])                                             \
        PAIR1(GA, c1, d1, XT1[0])                                             \
        RD(GA, BUF, 2)                                                        \
        PAIR1(GB, d0, c0, XT0[1])                                             \
        PAIR1(GB, d1, c1, XT1[1])                                             \
        RD(GB, BUF, 3)                                                        \
        PAIR1(GA, c0, d0, XT0[2])                                             \
        PAIR1(GA, c1, d1, XT1[2])                                             \
        PAIR1(GB, d0, c0, XT0[3])                                             \
        PAIR1(GB, d1, c1, XT1[3])                                             \
        __syncthreads();                                                      \
        if ((C) < 7) RD(GA, 1 - (BUF), 0)                                     \
    }

__global__ __launch_bounds__(128, 1) void mps_main(const float* __restrict__ x,
                                                   const _Float16* __restrict__ Gf,
                                                   float* __restrict__ out) {
    __shared__ __align__(16) _Float16 smA[2 * CHUNK_ELEMS];   // 64KB

    const int lane  = threadIdx.x & 63;
    const int wid   = threadIdx.x >> 6;               // 0..1
    const int wbase = (blockIdx.x * 2 + wid) * 64;    // 64 rows/wave (2 tiles of 32)
    const int col   = lane & 31;

    const f32x4* xp0 = reinterpret_cast<const f32x4*>(x + (size_t)(wbase + col) * 128);
    const f32x4* xp1 = reinterpret_cast<const f32x4*>(x + (size_t)(wbase + 32 + col) * 128);

    floatx16 zv;
#pragma unroll
    for (int i = 0; i < 16; ++i) zv[i] = 0.f;

    // acc: c0 = tile0 left, c1 = tile1 left; d* = ping-pong partners.
    // left[l], l = (reg&3) + 8*(reg>>2) + 4*(lane>>5)
    floatx16 c0, c1, d0, d1;
#pragma unroll
    for (int i = 0; i < 16; ++i) { c0[i] = 0.f; c1[i] = 0.f; d0[i] = 0.f; d1[i] = 0.f; }
    if (lane < 32) { c0[0] = 1.f; c1[0] = 1.f; }      // left0 = e0 (l=0: reg0, h=0)

    // x quads: pair P needs x[b][4P..4P+3] = (x0,x1,y0,y1) = f32x4 #P
    f32x4 xa0[4], xa1[4], xb0[4], xb1[4];
    half8 GA[8], GB[8];

    STAGE(0, 0);
#pragma unroll
    for (int pp = 0; pp < 4; ++pp) { xa0[pp] = xp0[pp]; xa1[pp] = xp1[pp]; }
    __syncthreads();
    RD(GA, 0, 0)

    CHUNKB(0, 0, xa0, xa1, xb0, xb1)
    CHUNKB(1, 1, xb0, xb1, xa0, xa1)
    CHUNKB(2, 0, xa0, xa1, xb0, xb1)
    CHUNKB(3, 1, xb0, xb1, xa0, xa1)
    CHUNKB(4, 0, xa0, xa1, xb0, xb1)
    CHUNKB(5, 1, xb0, xb1, xa0, xa1)
    CHUNKB(6, 0, xa0, xa1, xb0, xb1)
    CHUNKB(7, 1, xb0, xb1, xa0, xa1)

    // out[b] = left_final[l=0]: reg 0, h=0 -> lanes 0..31, col = lane
    if (lane < 32) {
        out[wbase + lane]      = c0[0];
        out[wbase + 32 + lane] = c1[0];
    }
}

extern "C" void kernel_launch(void* const* d_in, const int* in_sizes, int n_in,
                              void* d_out, int out_size, void* d_ws, size_t ws_size,
                              hipStream_t stream) {
    const float* x = (const float*)d_in[0];   // [65536][64][2] f32
    const float* A = (const float*)d_in[1];   // [64][32][2][32] f32
    float* outp = (float*)d_out;              // [65536] f32
    _Float16* Gf = (_Float16*)d_ws;           // 256 KB pair-fragment fp16

    hipLaunchKernelGGL(mps_prep_pair, dim3(NPAIRS), dim3(256), 0, stream, A, Gf);
    hipLaunchKernelGGL(mps_main, dim3(65536 / 128), dim3(128), 0, stream, x, Gf, outp);
}